// Round 3
// baseline (336.996 us; speedup 1.0000x reference)
//
#include <hip/hip_runtime.h>

#define B_ 128
#define T_ 2048
#define N_ 64
#define L_ 256
#define NEGV (-1e30f)
#define PITCH 72   // shorts per LDS row (64 + 8 pad) for k2 staging
#define LOG2E 1.4426950408889634f
#define LN2   0.6931471805599453f

typedef short  s16x4 __attribute__((ext_vector_type(4)));
typedef short  s16x8 __attribute__((ext_vector_type(8)));
typedef float  f32x4 __attribute__((ext_vector_type(4)));
typedef float  f32x16 __attribute__((ext_vector_type(16)));
typedef unsigned int u32x2 __attribute__((ext_vector_type(2)));
typedef unsigned int u32x4 __attribute__((ext_vector_type(4)));

__device__ __forceinline__ short f2bf_rne(float f) {
    unsigned u = __float_as_uint(f);
    unsigned r = (u + 0x7FFFu + ((u >> 16) & 1u)) >> 16;
    return (short)r;
}
__device__ __forceinline__ float bf2f(unsigned short u) {
    return __uint_as_float(((unsigned)u) << 16);
}
__device__ __forceinline__ float bperm(int byteaddr, float v) {
    return __int_as_float(__builtin_amdgcn_ds_bpermute(byteaddr, __float_as_int(v)));
}
// logaddexp in log2 domain (v_exp_f32/v_log_f32 are base-2)
__device__ __forceinline__ float lse2b(float p, float q) {
    float mx = fmaxf(p, q);
    float t  = __builtin_amdgcn_exp2f(-fabsf(p - q));
    return mx + __builtin_amdgcn_logf(1.f + t);
}
// pack 2 f32 -> 2 bf16 (RNE) in one u32
__device__ __forceinline__ unsigned cvtpk_bf16(float lo, float hi) {
    unsigned r;
    asm("v_cvt_pk_bf16_f32 %0, %1, %2" : "=v"(r) : "v"(lo), "v"(hi));
    return r;
}
// swap upper 32 lanes of x with lower 32 lanes of y
__device__ __forceinline__ void plswap32(unsigned &x, unsigned &y) {
    asm("v_permlane32_swap_b32 %0, %1" : "+v"(x), "+v"(y));
}

// Kernel 1: blocks 0..255 carry one FAC wave (wid 0: fwd for bx<128, bwd for
// bx<256) + 3 FCC waves; blocks 256..1087 are 4 FCC waves. Spreading the 256
// long-running FAC waves across ~all CUs lets their VALU issue hide under the
// FCC matrix span instead of forming a 150us 1-wave/SIMD tail on 64 CUs.
__global__ __launch_bounds__(256, 2) void asg_k1(
    const float* __restrict__ x,       // (B,T,N)
    const int*   __restrict__ target,  // (B,L)
    const int*   __restrict__ tsize,   // (B,)
    const float* __restrict__ trans,   // (N,N)
    float* __restrict__ ws_c,          // (B,32) chunk log-scales
    unsigned short* __restrict__ ws_R, // (B,32,64,64) bf16 chunk matrices [m][n]
    float* __restrict__ ws_v,          // (B,256) alpha_1023 (log2 domain)
    float* __restrict__ ws_w)          // (B,256) beta_1023  (log2 domain)
{
    __shared__ float evbuf[4][N_];     // per-wave ev broadcast buffer (FCC)
    const int wid  = threadIdx.x >> 6;
    const int lane = threadIdx.x & 63;
    const int bx   = blockIdx.x;
    const bool isfac = (bx < 256) && (wid == 0);

    if (isfac && bx < 128) {
        // ---------------- FAC forward: alpha_0 .. alpha_1023 ----------------
        // Emissions gathered directly from global (4-step prefetch ring);
        // only the alpha-boundary bperm (1-step slack) touches LDS.
        const int b  = bx;
        const float* __restrict__ xb = x + (size_t)b * T_ * N_;
        const int l0 = lane * 4;
        int tg[4]; float slf[4], mv[4], a[4];
        #pragma unroll
        for (int j = 0; j < 4; ++j) {
            const int tv = target[b * L_ + l0 + j];
            tg[j] = tv;
            slf[j] = trans[tv * N_ + tv] * LOG2E;
            if (j > 0) mv[j] = trans[tv * N_ + (target[b * L_ + l0 + j - 1])] * LOG2E;
            a[j] = NEGV;
        }
        const int tR  = target[b * L_ + ((l0 - 1 >= 0) ? l0 - 1 : 0)];
        const int tR1 = target[b * L_ + ((l0 - 2 >= 0) ? l0 - 2 : 0)];
        const float slfR = trans[tR * N_ + tR] * LOG2E;
        const float mvR  = trans[tR * N_ + tR1] * LOG2E;
        mv[0] = trans[tg[0] * N_ + tR] * LOG2E;
        if (lane == 0) a[0] = xb[tg[0]] * LOG2E;   // alpha0[0]
        float red = NEGV;
        float bp  = NEGV;                           // alpha_0[l0-2] == NEGV always
        const int upA = ((lane == 0) ? 0 : lane - 1) << 2;

        // prefetch ring: raw emissions for t = 1..4
        float E[4][5];
        #pragma unroll
        for (int d = 0; d < 4; ++d) {
            const float* __restrict__ xp = xb + (size_t)(1 + d) * N_;
            E[d][0] = xp[tg[0]]; E[d][1] = xp[tg[1]];
            E[d][2] = xp[tg[2]]; E[d][3] = xp[tg[3]];
            E[d][4] = xp[tR];
        }

        #define FWD_STEP(t, i)                                                  \
        {                                                                       \
            const float c0 = E[i][0], c1 = E[i][1], c2 = E[i][2],               \
                        c3 = E[i][3], cR = E[i][4];                             \
            const int rw = ((t) + 4 <= 1023) ? (t) + 4 : 1023;                  \
            const float* __restrict__ xp = xb + (size_t)rw * N_;                \
            E[i][0] = xp[tg[0]]; E[i][1] = xp[tg[1]];                           \
            E[i][2] = xp[tg[2]]; E[i][3] = xp[tg[3]];                           \
            E[i][4] = xp[tR];                                                   \
            const float n0 = fmaf(c0, LOG2E, lse2b(a[0] + slf[0], red  + mv[0]));\
            const float n1 = fmaf(c1, LOG2E, lse2b(a[1] + slf[1], a[0] + mv[1]));\
            const float n2 = fmaf(c2, LOG2E, lse2b(a[2] + slf[2], a[1] + mv[2]));\
            const float n3 = fmaf(c3, LOG2E, lse2b(a[3] + slf[3], a[2] + mv[3]));\
            const float nr = fmaf(cR, LOG2E, lse2b(red + slfR,    bp   + mvR)); \
            bp = bperm(upA, n2);                                                \
            a[0] = n0; a[1] = n1; a[2] = n2; a[3] = n3;                         \
            red = (lane == 0) ? NEGV : nr;                                      \
        }
        for (int u = 0; u < 255; ++u) {                 // t = 1..1020
            const int tb = 1 + 4 * u;
            #pragma unroll
            for (int i = 0; i < 4; ++i) FWD_STEP(tb + i, i);
        }
        FWD_STEP(1021, 0); FWD_STEP(1022, 1); FWD_STEP(1023, 2);
        #undef FWD_STEP
        *(float4*)(ws_v + b * 256 + l0) = make_float4(a[0], a[1], a[2], a[3]);
    } else if (isfac) {
        // ---------------- FAC backward: beta_2047 .. beta_1023 ----------------
        const int b  = bx - 128;
        const float* __restrict__ xb = x + (size_t)b * T_ * N_;
        const int l0 = lane * 4;
        const int lt = tsize[b] - 1;
        int tg[4]; float slf[4], mvin[4], a[4];
        #pragma unroll
        for (int j = 0; j < 4; ++j) {
            const int tv = target[b * L_ + l0 + j];
            tg[j] = tv;
            slf[j] = trans[tv * N_ + tv] * LOG2E;
            if (j > 0) mvin[j] = trans[tv * N_ + (target[b * L_ + l0 + j - 1])] * LOG2E;
            a[j] = (l0 + j == lt) ? 0.f : NEGV;
        }
        const int tR  = target[b * L_ + ((l0 + 4 <= L_ - 1) ? l0 + 4 : L_ - 1)];
        const int tR2 = target[b * L_ + ((l0 + 5 <= L_ - 1) ? l0 + 5 : L_ - 1)];
        const float slfR = trans[tR * N_ + tR] * LOG2E;
        const float mvR  = trans[tR * N_ + tg[3]] * LOG2E;  // move into 4m+4
        const float mvR2 = trans[tR2 * N_ + tR] * LOG2E;    // move into 4m+5
        float red = (l0 + 4 == lt) ? 0.f : NEGV;
        float bp  = (l0 + 5 == lt) ? 0.f : NEGV;            // beta_init[l0+5]
        const int dnA = ((lane == 63) ? 63 : lane + 1) << 2;

        // prefetch ring: raw emissions for t = 2047..2044
        float E[4][6];
        #pragma unroll
        for (int d = 0; d < 4; ++d) {
            const float* __restrict__ xp = xb + (size_t)(2047 - d) * N_;
            E[d][0] = xp[tg[0]]; E[d][1] = xp[tg[1]];
            E[d][2] = xp[tg[2]]; E[d][3] = xp[tg[3]];
            E[d][4] = xp[tR];    E[d][5] = xp[tR2];
        }

        #define BWD_STEP(t, i)                                                  \
        {                                                                       \
            const float c0 = E[i][0], c1 = E[i][1], c2 = E[i][2],               \
                        c3 = E[i][3], cR = E[i][4], cR2 = E[i][5];              \
            const int rw = ((t) - 4 >= 1024) ? (t) - 4 : 1024;                  \
            const float* __restrict__ xp = xb + (size_t)rw * N_;                \
            E[i][0] = xp[tg[0]]; E[i][1] = xp[tg[1]];                           \
            E[i][2] = xp[tg[2]]; E[i][3] = xp[tg[3]];                           \
            E[i][4] = xp[tR];    E[i][5] = xp[tR2];                             \
            const float t0 = fmaf(c0, LOG2E, a[0]), t1 = fmaf(c1, LOG2E, a[1]); \
            const float t2 = fmaf(c2, LOG2E, a[2]), t3 = fmaf(c3, LOG2E, a[3]); \
            const float tr = fmaf(cR, LOG2E, red);                              \
            const float n0 = lse2b(t0 + slf[0], t1 + mvin[1]);                  \
            const float n1 = lse2b(t1 + slf[1], t2 + mvin[2]);                  \
            const float n2 = lse2b(t2 + slf[2], t3 + mvin[3]);                  \
            const float n3 = lse2b(t3 + slf[3], tr + mvR);                      \
            const float nr = lse2b(tr + slfR, bp + fmaf(cR2, LOG2E, mvR2));     \
            bp = bperm(dnA, n1);                                                \
            a[0] = n0; a[1] = n1; a[2] = n2; a[3] = n3;                         \
            red = (lane == 63) ? NEGV : nr;                                     \
        }
        for (int u = 0; u < 256; ++u) {                 // t = 2047..1024
            const int tb = 2047 - 4 * u;
            #pragma unroll
            for (int i = 0; i < 4; ++i) BWD_STEP(tb - i, i);
        }
        #undef BWD_STEP
        *(float4*)(ws_w + b * 256 + l0) = make_float4(a[0], a[1], a[2], a[3]);
    } else {
        // ---------------- FCC chunk: P = prod_s D_t*Ehat over 64 steps --------
        // 32x32x16 MFMA, product kept entirely in registers as B-operand frags.
        // Layouts (gfx950): C/D: col=lane&31, row=(reg&3)+8*(reg>>2)+4*(lane>>5)
        //                   A:   row=lane&31, k = 16*kt + 8*(lane>>5) + j
        //                   B:   col=lane&31, k = 16*kt + 8*(lane>>5) + j
        const int task = (bx < 256) ? (bx * 3 + wid - 1)
                                    : (768 + (bx - 256) * 4 + wid);   // 0..4095
        const int b = task >> 5, k = task & 31;
        const int lane31 = lane & 31, hi = lane >> 5;
        const float* __restrict__ xb = x + (size_t)b * T_ * N_;
        const int t0 = k * 64;
        float* __restrict__ evb = evbuf[wid];

        // A-operand: Ahat[r][kt] = exp(trans[32r+lane31][16kt+8hi+j])
        s16x8 Ahat[2][4];
        float rsum[2];
        #pragma unroll
        for (int r = 0; r < 2; ++r) {
            float rs = 0.f;
            const float* tp = trans + (32 * r + lane31) * N_;
            #pragma unroll
            for (int kt = 0; kt < 4; ++kt) {
                const float* tq = tp + 16 * kt + 8 * hi;
                float4 ta = *(const float4*)tq;
                float4 tb = *(const float4*)(tq + 4);
                float v0 = __expf(ta.x), v1 = __expf(ta.y),
                      v2 = __expf(ta.z), v3 = __expf(ta.w);
                float v4 = __expf(tb.x), v5 = __expf(tb.y),
                      v6 = __expf(tb.z), v7 = __expf(tb.w);
                s16x8 af;
                af[0] = f2bf_rne(v0); af[1] = f2bf_rne(v1);
                af[2] = f2bf_rne(v2); af[3] = f2bf_rne(v3);
                af[4] = f2bf_rne(v4); af[5] = f2bf_rne(v5);
                af[6] = f2bf_rne(v6); af[7] = f2bf_rne(v7);
                rs += ((v0 + v1) + (v2 + v3)) + ((v4 + v5) + (v6 + v7));
                Ahat[r][kt] = af;
            }
            rsum[r] = rs;
        }
        rsum[0] += __shfl_xor(rsum[0], 32);
        rsum[1] += __shfl_xor(rsum[1], 32);
        float rmax = fmaxf(rsum[0], rsum[1]);
        #pragma unroll
        for (int o = 16; o > 0; o >>= 1) rmax = fmaxf(rmax, __shfl_xor(rmax, o));
        const float LS = __logf(rmax);

        // B-operand: identity
        s16x8 Pf[4][2];
        #pragma unroll
        for (int kt = 0; kt < 4; ++kt)
            #pragma unroll
            for (int c = 0; c < 2; ++c) {
                s16x8 pf;
                #pragma unroll
                for (int j = 0; j < 8; ++j)
                    pf[j] = (16 * kt + 8 * hi + j == 32 * c + lane31)
                              ? (short)0x3F80 : (short)0;
                Pf[kt][c] = pf;
            }

        const f32x16 z16 = {};          // zero accumulator seed (kept live)
        f32x16 Y00 = {}, Y01 = {}, Y10 = {}, Y11 = {};
        float xpre[4];
        #pragma unroll
        for (int d = 0; d < 4; ++d)
            xpre[d] = xb[(size_t)(t0 + 1 + d) * N_ + lane];
        float c_acc = 0.f;

        #define MM(af, bf, cf) __builtin_amdgcn_mfma_f32_32x32x16_bf16(af, bf, cf, 0, 0, 0)
        // feedback: Pf'[kt][c] words = {plswap(P0,Q0), plswap(P1,Q1)} of scaled-Y regs
        #define REDIST(kt, c, Yv)                                               \
        {                                                                       \
            unsigned P0 = cvtpk_bf16(Yv[8*((kt)&1) + 0], Yv[8*((kt)&1) + 1]);   \
            unsigned P1 = cvtpk_bf16(Yv[8*((kt)&1) + 2], Yv[8*((kt)&1) + 3]);   \
            unsigned Q0 = cvtpk_bf16(Yv[8*((kt)&1) + 4], Yv[8*((kt)&1) + 5]);   \
            unsigned Q1 = cvtpk_bf16(Yv[8*((kt)&1) + 6], Yv[8*((kt)&1) + 7]);   \
            plswap32(P0, Q0); plswap32(P1, Q1);                                 \
            u32x4 uv; uv[0] = P0; uv[1] = P1; uv[2] = Q0; uv[3] = Q1;           \
            Pf[kt][c] = __builtin_bit_cast(s16x8, uv);                          \
        }

        #pragma unroll 1
        for (int u = 0; u < 16; ++u) {
            #pragma unroll
            for (int i = 0; i < 4; ++i) {
                const int s = 4 * u + i;
                const int t = t0 + 1 + s;
                if (t < T_) {
                    const float xt = xpre[i];
                    int tp2 = t + 4; if (tp2 > T_ - 1) tp2 = T_ - 1;
                    xpre[i] = xb[(size_t)tp2 * N_ + lane];
                    const float gt = __uint_as_float(
                        __builtin_amdgcn_readfirstlane(__float_as_uint(xt))) + LS;
                    c_acc += gt;
                    evb[lane] = __expf(xt - gt);     // ds_write, in-order w/ reads
                    float4 E[2][4];
                    #pragma unroll
                    for (int r = 0; r < 2; ++r)
                        #pragma unroll
                        for (int q = 0; q < 4; ++q)
                            E[r][q] = *(const float4*)&evb[32 * r + 8 * q + 4 * hi];
                    // Y = Ehat * P  (16 mfma, LDS latency hides underneath)
                    Y00 = MM(Ahat[0][0], Pf[0][0], z16);
                    Y01 = MM(Ahat[0][0], Pf[0][1], z16);
                    Y10 = MM(Ahat[1][0], Pf[0][0], z16);
                    Y11 = MM(Ahat[1][0], Pf[0][1], z16);
                    #pragma unroll
                    for (int kt = 1; kt < 4; ++kt) {
                        Y00 = MM(Ahat[0][kt], Pf[kt][0], Y00);
                        Y01 = MM(Ahat[0][kt], Pf[kt][1], Y01);
                        Y10 = MM(Ahat[1][kt], Pf[kt][0], Y10);
                        Y11 = MM(Ahat[1][kt], Pf[kt][1], Y11);
                    }
                    // row scale: row = 32r + 8q + 4hi + m  <->  reg = 4q + m
                    #pragma unroll
                    for (int q = 0; q < 4; ++q) {
                        Y00[4*q+0] *= E[0][q].x; Y00[4*q+1] *= E[0][q].y;
                        Y00[4*q+2] *= E[0][q].z; Y00[4*q+3] *= E[0][q].w;
                        Y01[4*q+0] *= E[0][q].x; Y01[4*q+1] *= E[0][q].y;
                        Y01[4*q+2] *= E[0][q].z; Y01[4*q+3] *= E[0][q].w;
                        Y10[4*q+0] *= E[1][q].x; Y10[4*q+1] *= E[1][q].y;
                        Y10[4*q+2] *= E[1][q].z; Y10[4*q+3] *= E[1][q].w;
                        Y11[4*q+0] *= E[1][q].x; Y11[4*q+1] *= E[1][q].y;
                        Y11[4*q+2] *= E[1][q].z; Y11[4*q+3] *= E[1][q].w;
                    }
                    // in-register feedback into B-operand fragments
                    REDIST(0, 0, Y00); REDIST(0, 1, Y01);
                    REDIST(1, 0, Y00); REDIST(1, 1, Y01);
                    REDIST(2, 0, Y10); REDIST(2, 1, Y11);
                    REDIST(3, 0, Y10); REDIST(3, 1, Y11);
                }
            }
        }
        #undef REDIST
        #undef MM

        // store P[m][n] bf16: row = 32r + 8q + 4hi + m, col = 32c + lane31
        unsigned short* dst = ws_R + (size_t)(b * 32 + k) * 4096;
        #pragma unroll
        for (int q = 0; q < 4; ++q)
            #pragma unroll
            for (int m = 0; m < 4; ++m) {
                const int reg = 4 * q + m;
                const int rw  = 8 * q + 4 * hi + m;
                dst[(rw     ) * 64 + lane31     ] = (unsigned short)f2bf_rne(Y00[reg]);
                dst[(rw     ) * 64 + 32 + lane31] = (unsigned short)f2bf_rne(Y01[reg]);
                dst[(32 + rw) * 64 + lane31     ] = (unsigned short)f2bf_rne(Y10[reg]);
                dst[(32 + rw) * 64 + 32 + lane31] = (unsigned short)f2bf_rne(Y11[reg]);
            }
        if (lane == 0) ws_c[b * 32 + k] = c_acc;
    }
}

// Kernel 2: wave0 = fcc chunk combine (LDS-staged, depth-2 register prefetch,
// per-iteration max-rescale); wave1 = fwd/bwd fac combine. One block per batch.
__global__ __launch_bounds__(128) void asg_k2(
    const float* __restrict__ x,
    const float* __restrict__ ws_c,
    const unsigned short* __restrict__ ws_R,
    const float* __restrict__ ws_v,
    const float* __restrict__ ws_w,
    float* __restrict__ out)
{
    __shared__ short rb[2][N_ * PITCH];
    __shared__ __align__(16) float sa[N_];
    __shared__ float sres[2];
    const int b = blockIdx.x, tid = threadIdx.x, lane = tid & 63;

    if (tid < 64) {
        float a0 = x[(size_t)b * T_ * N_ + lane];
        float m0 = a0;
        #pragma unroll
        for (int o = 32; o > 0; o >>= 1) m0 = fmaxf(m0, __shfl_xor(m0, o));
        float  a  = __expf(a0 - m0);
        double Cd = (double)m0;

        const unsigned short* Rb = ws_R + (size_t)b * 32 * 4096;
        const int frow = (lane >> 3), fcol = (lane & 7) * 8;  // staging lane slot
        // preload chunk 0 -> buf 0 (coalesced b128)
        {
            #pragma unroll
            for (int q = 0; q < 8; ++q) {
                s16x8 v = *(const s16x8*)(Rb + lane * 8 + 512 * q);
                *(s16x8*)&rb[0][(frow + 8 * q) * PITCH + fcol] = v;
            }
        }
        // issue chunk-1 loads
        s16x8 nvA[8], nvB[8];
        #pragma unroll
        for (int q = 0; q < 8; ++q)
            nvA[q] = *(const s16x8*)(Rb + (size_t)4096 + lane * 8 + 512 * q);

        // one chunk application: a <- normalize((R_kk)·a), Cd += scales
        auto k2_step = [&](int kk, int bufi) {
            sa[lane] = a;
            float4 sav[16];
            #pragma unroll
            for (int q = 0; q < 16; ++q) sav[q] = ((const float4*)sa)[q];
            float acc4[4] = {0.f, 0.f, 0.f, 0.f};
            #pragma unroll
            for (int u = 0; u < 8; ++u) {
                s16x8 rr = *(const s16x8*)&rb[bufi][lane * PITCH + u * 8];
                const float4 s0 = sav[2 * u], s1 = sav[2 * u + 1];
                acc4[0] = fmaf(bf2f((unsigned short)rr[0]), s0.x, acc4[0]);
                acc4[1] = fmaf(bf2f((unsigned short)rr[1]), s0.y, acc4[1]);
                acc4[2] = fmaf(bf2f((unsigned short)rr[2]), s0.z, acc4[2]);
                acc4[3] = fmaf(bf2f((unsigned short)rr[3]), s0.w, acc4[3]);
                acc4[0] = fmaf(bf2f((unsigned short)rr[4]), s1.x, acc4[0]);
                acc4[1] = fmaf(bf2f((unsigned short)rr[5]), s1.y, acc4[1]);
                acc4[2] = fmaf(bf2f((unsigned short)rr[6]), s1.z, acc4[2]);
                acc4[3] = fmaf(bf2f((unsigned short)rr[7]), s1.w, acc4[3]);
            }
            float acc = (acc4[0] + acc4[1]) + (acc4[2] + acc4[3]);
            float rm = acc;
            #pragma unroll
            for (int o = 32; o > 0; o >>= 1) rm = fmaxf(rm, __shfl_xor(rm, o));
            a = acc / rm;
            Cd += (double)(__logf(rm) + ws_c[b * 32 + kk]);
        };

        for (int kk = 0; kk < 32; kk += 2) {
            // even iter: prefetch chunk kk+2 -> nvB, compute rb[kk&1], stage nvA
            const int kA = (kk + 2 < 32) ? kk + 2 : 31;
            #pragma unroll
            for (int q = 0; q < 8; ++q)
                nvB[q] = *(const s16x8*)(Rb + (size_t)kA * 4096 + lane * 8 + 512 * q);
            k2_step(kk, kk & 1);
            #pragma unroll
            for (int q = 0; q < 8; ++q)
                *(s16x8*)&rb[(kk + 1) & 1][(frow + 8 * q) * PITCH + fcol] = nvA[q];
            // odd iter: prefetch chunk kk+3 -> nvA, compute rb[(kk+1)&1], stage nvB
            const int kB = (kk + 3 < 32) ? kk + 3 : 31;
            #pragma unroll
            for (int q = 0; q < 8; ++q)
                nvA[q] = *(const s16x8*)(Rb + (size_t)kB * 4096 + lane * 8 + 512 * q);
            k2_step(kk + 1, (kk + 1) & 1);
            #pragma unroll
            for (int q = 0; q < 8; ++q)
                *(s16x8*)&rb[kk & 1][(frow + 8 * q) * PITCH + fcol] = nvB[q];
        }
        float ssum = a;
        #pragma unroll
        for (int o = 32; o > 0; o >>= 1) ssum += __shfl_xor(ssum, o);
        if (lane == 0) sres[0] = (float)(Cd + (double)__logf(ssum));
    } else {
        // fac combine: F = ln-domain lse over 256 cells of (alpha+beta), log2 inputs
        float4 v4 = ((const float4*)(ws_v + b * 256))[lane];
        float4 w4 = ((const float4*)(ws_w + b * 256))[lane];
        const float s0 = v4.x + w4.x, s1 = v4.y + w4.y,
                    s2 = v4.z + w4.z, s3 = v4.w + w4.w;
        float m = fmaxf(fmaxf(s0, s1), fmaxf(s2, s3));
        #pragma unroll
        for (int o = 32; o > 0; o >>= 1) m = fmaxf(m, __shfl_xor(m, o));
        float sum = __builtin_amdgcn_exp2f(s0 - m) + __builtin_amdgcn_exp2f(s1 - m)
                  + __builtin_amdgcn_exp2f(s2 - m) + __builtin_amdgcn_exp2f(s3 - m);
        #pragma unroll
        for (int o = 32; o > 0; o >>= 1) sum += __shfl_xor(sum, o);
        if (lane == 0) sres[1] = (m + __builtin_amdgcn_logf(sum)) * LN2;
    }
    __syncthreads();
    if (tid == 0) out[b] = sres[0] - sres[1];
}

extern "C" void kernel_launch(void* const* d_in, const int* in_sizes, int n_in,
                              void* d_out, int out_size, void* d_ws, size_t ws_size,
                              hipStream_t stream) {
    (void)in_sizes; (void)n_in; (void)out_size; (void)ws_size;
    const float* xin    = (const float*)d_in[0];
    const int*   target = (const int*)  d_in[1];
    const int*   tsz    = (const int*)  d_in[2];
    const float* trans  = (const float*)d_in[3];
    float* out = (float*)d_out;

    float*          ws_c = (float*)d_ws;                                    // 16 KB
    unsigned short* ws_R = (unsigned short*)((char*)d_ws + 16384);          // 33.55 MB
    float*          ws_v = (float*)((char*)d_ws + 16384 + 33554432);        // 128 KB
    float*          ws_w = (float*)((char*)d_ws + 16384 + 33554432 + 131072);

    // blocks 0..255: 1 fac wave + 3 fcc waves; blocks 256..1087: 4 fcc waves
    asg_k1<<<dim3(1088), dim3(256), 0, stream>>>(xin, target, tsz, trans,
                                                 ws_c, ws_R, ws_v, ws_w);
    asg_k2<<<dim3(B_), dim3(128), 0, stream>>>(xin, ws_c, ws_R, ws_v, ws_w, out);
}

// Round 4
// 316.899 us; speedup vs baseline: 1.0634x; 1.0634x over previous
//
#include <hip/hip_runtime.h>

#define B_ 128
#define T_ 2048
#define N_ 64
#define L_ 256
#define NEGV (-1e30f)
#define PITCH 72   // shorts per LDS row (64 + 8 pad) for k2 staging
#define LOG2E 1.4426950408889634f
#define LN2   0.6931471805599453f

typedef short  s16x4 __attribute__((ext_vector_type(4)));
typedef short  s16x8 __attribute__((ext_vector_type(8)));
typedef float  f32x4 __attribute__((ext_vector_type(4)));
typedef float  f32x16 __attribute__((ext_vector_type(16)));
typedef unsigned int u32x2 __attribute__((ext_vector_type(2)));
typedef unsigned int u32x4 __attribute__((ext_vector_type(4)));

__device__ __forceinline__ short f2bf_rne(float f) {
    unsigned u = __float_as_uint(f);
    unsigned r = (u + 0x7FFFu + ((u >> 16) & 1u)) >> 16;
    return (short)r;
}
__device__ __forceinline__ float bf2f(unsigned short u) {
    return __uint_as_float(((unsigned)u) << 16);
}
__device__ __forceinline__ float bperm(int byteaddr, float v) {
    return __int_as_float(__builtin_amdgcn_ds_bpermute(byteaddr, __float_as_int(v)));
}
// logaddexp in log2 domain (v_exp_f32/v_log_f32 are base-2)
__device__ __forceinline__ float lse2b(float p, float q) {
    float mx = fmaxf(p, q);
    float t  = __builtin_amdgcn_exp2f(-fabsf(p - q));
    return mx + __builtin_amdgcn_logf(1.f + t);
}
// pack 2 f32 -> 2 bf16 (RNE) in one u32
__device__ __forceinline__ unsigned cvtpk_bf16(float lo, float hi) {
    unsigned r;
    asm("v_cvt_pk_bf16_f32 %0, %1, %2" : "=v"(r) : "v"(lo), "v"(hi));
    return r;
}
// swap upper 32 lanes of x with lower 32 lanes of y
__device__ __forceinline__ void plswap32(unsigned &x, unsigned &y) {
    asm("v_permlane32_swap_b32 %0, %1" : "+v"(x), "+v"(y));
}

// Kernel 1: blocks 0..255 carry one FAC wave (wid 0: fwd for bx<128, bwd for
// bx<256) + 3 FCC waves; blocks 256..1087 are 4 FCC waves. FAC uses the
// round-1-proven bperm recurrence (coalesced row load + LDS-pipe broadcast);
// spreading overlaps the ~150us FAC span with the ~55us FCC matrix span.
__global__ __launch_bounds__(256, 2) void asg_k1(
    const float* __restrict__ x,       // (B,T,N)
    const int*   __restrict__ target,  // (B,L)
    const int*   __restrict__ tsize,   // (B,)
    const float* __restrict__ trans,   // (N,N)
    float* __restrict__ ws_c,          // (B,32) chunk log-scales
    unsigned short* __restrict__ ws_R, // (B,32,64,64) bf16 chunk matrices [m][n]
    float* __restrict__ ws_v,          // (B,256) alpha_1023 (log2 domain)
    float* __restrict__ ws_w)          // (B,256) beta_1023  (log2 domain)
{
    __shared__ float evbuf[4][N_];     // per-wave ev broadcast buffer (FCC)
    const int wid  = threadIdx.x >> 6;
    const int lane = threadIdx.x & 63;
    const int bx   = blockIdx.x;
    const bool isfac = (bx < 256) && (wid == 0);

    if (isfac && bx < 128) {
        // ---------------- FAC forward: alpha_0 .. alpha_1023 ----------------
        const int b  = bx;
        const float* __restrict__ xb = x + (size_t)b * T_ * N_;
        const int l0 = lane * 4;
        int tga[4]; float slf[4], mv[4], a[4];
        #pragma unroll
        for (int j = 0; j < 4; ++j) {
            const int tv = target[b * L_ + l0 + j];
            tga[j] = tv << 2;
            slf[j] = trans[tv * N_ + tv] * LOG2E;
            if (j > 0) mv[j] = trans[tv * N_ + (target[b * L_ + l0 + j - 1])] * LOG2E;
            a[j] = NEGV;
        }
        const int tR  = target[b * L_ + ((l0 - 1 >= 0) ? l0 - 1 : 0)];
        const int tR1 = target[b * L_ + ((l0 - 2 >= 0) ? l0 - 2 : 0)];
        const int tgR = tR << 2;
        const float slfR = trans[tR * N_ + tR] * LOG2E;
        const float mvR  = trans[tR * N_ + tR1] * LOG2E;
        mv[0] = trans[(tga[0] >> 2) * N_ + tR] * LOG2E;
        if (lane == 0) a[0] = xb[tga[0] >> 2] * LOG2E;   // alpha0[0]
        float red = NEGV;
        const int upA = ((lane == 0) ? 0 : lane - 1) << 2;

        float xr[16];
        #pragma unroll
        for (int i = 0; i < 16; ++i) xr[i] = xb[(size_t)(1 + i) * N_ + lane];
        float sc = xr[0] * LOG2E;
        float eR = bperm(tgR, sc);
        float e0 = bperm(tga[0], sc), e1 = bperm(tga[1], sc),
              e2 = bperm(tga[2], sc), e3 = bperm(tga[3], sc);
        float bp = bperm(upA, a[2]);

        #define FWD_STEP(i, rp, RF)                                             \
        {                                                                       \
            const float ceR = eR, c0 = e0, c1 = e1, c2 = e2, c3 = e3;           \
            float scn = xr[((i) + 1) & 15] * LOG2E;                             \
            eR = bperm(tgR, scn);                                               \
            e0 = bperm(tga[0], scn); e1 = bperm(tga[1], scn);                   \
            e2 = bperm(tga[2], scn); e3 = bperm(tga[3], scn);                   \
            if (RF) xr[i] = (rp)[lane];                                         \
            const float n0 = lse2b(a[0] + slf[0], red  + mv[0]) + c0;           \
            const float n1 = lse2b(a[1] + slf[1], a[0] + mv[1]) + c1;           \
            const float n2 = lse2b(a[2] + slf[2], a[1] + mv[2]) + c2;           \
            const float n3 = lse2b(a[3] + slf[3], a[2] + mv[3]) + c3;           \
            const float nr = lse2b(red + slfR,    bp   + mvR)   + ceR;          \
            bp = bperm(upA, n2);                                                \
            a[0] = n0; a[1] = n1; a[2] = n2; a[3] = n3;                         \
            red = (lane == 0) ? NEGV : nr;                                      \
        }
        for (int u = 0; u < 63; ++u) {                  // t = 1..1008
            const float* __restrict__ xp = xb + (size_t)(16 * u + 17) * N_;
            #pragma unroll
            for (int i = 0; i < 16; ++i) FWD_STEP(i, xp + i * N_, true);
        }
        #pragma unroll
        for (int i = 0; i < 15; ++i) FWD_STEP(i, xb, false);   // t = 1009..1023
        #undef FWD_STEP
        *(float4*)(ws_v + b * 256 + l0) = make_float4(a[0], a[1], a[2], a[3]);
    } else if (isfac) {
        // ---------------- FAC backward: beta_2047 .. beta_1023 ----------------
        const int b  = bx - 128;
        const float* __restrict__ xb = x + (size_t)b * T_ * N_;
        const int l0 = lane * 4;
        const int lt = tsize[b] - 1;
        int tga[4]; float slf[4], mvin[4], a[4];
        #pragma unroll
        for (int j = 0; j < 4; ++j) {
            const int tv = target[b * L_ + l0 + j];
            tga[j] = tv << 2;
            slf[j] = trans[tv * N_ + tv] * LOG2E;
            if (j > 0) mvin[j] = trans[tv * N_ + (target[b * L_ + l0 + j - 1])] * LOG2E;
            a[j] = (l0 + j == lt) ? 0.f : NEGV;
        }
        const int tR  = target[b * L_ + ((l0 + 4 <= L_ - 1) ? l0 + 4 : L_ - 1)];
        const int tR2 = target[b * L_ + ((l0 + 5 <= L_ - 1) ? l0 + 5 : L_ - 1)];
        const int tgR = tR << 2, tgR2 = tR2 << 2;
        const float slfR = trans[tR * N_ + tR] * LOG2E;
        const float mvR  = trans[tR * N_ + (tga[3] >> 2)] * LOG2E;  // move into 4m+4
        const float mvR2 = trans[tR2 * N_ + tR] * LOG2E;            // move into 4m+5
        float red = (l0 + 4 == lt) ? 0.f : NEGV;
        const int dnA = ((lane == 63) ? 63 : lane + 1) << 2;

        float xr[16];
        #pragma unroll
        for (int i = 0; i < 16; ++i) xr[i] = xb[(size_t)(2047 - i) * N_ + lane];
        float sc = xr[0] * LOG2E;
        float eR = bperm(tgR, sc), eR2 = bperm(tgR2, sc);
        float e0 = bperm(tga[0], sc), e1 = bperm(tga[1], sc),
              e2 = bperm(tga[2], sc), e3 = bperm(tga[3], sc);
        float bp = bperm(dnA, a[1]);

        #define BWD_STEP(i, rp, RF)                                             \
        {                                                                       \
            const float ceR = eR, ceR2 = eR2, c0 = e0, c1 = e1, c2 = e2, c3 = e3;\
            float scn = xr[((i) + 1) & 15] * LOG2E;                             \
            eR = bperm(tgR, scn); eR2 = bperm(tgR2, scn);                       \
            e0 = bperm(tga[0], scn); e1 = bperm(tga[1], scn);                   \
            e2 = bperm(tga[2], scn); e3 = bperm(tga[3], scn);                   \
            if (RF) xr[i] = (rp)[lane];                                         \
            const float t0 = a[0] + c0, t1 = a[1] + c1, t2 = a[2] + c2,         \
                        t3 = a[3] + c3, tr = red + ceR;                         \
            const float n0 = lse2b(t0 + slf[0], t1 + mvin[1]);                  \
            const float n1 = lse2b(t1 + slf[1], t2 + mvin[2]);                  \
            const float n2 = lse2b(t2 + slf[2], t3 + mvin[3]);                  \
            const float n3 = lse2b(t3 + slf[3], tr + mvR);                      \
            const float nr = lse2b(tr + slfR, bp + ceR2 + mvR2);                \
            bp = bperm(dnA, n1);                                                \
            a[0] = n0; a[1] = n1; a[2] = n2; a[3] = n3;                         \
            red = (lane == 63) ? NEGV : nr;                                     \
        }
        for (int u = 0; u < 63; ++u) {                  // t = 2047..1040
            const float* __restrict__ xp = xb + (size_t)(2047 - 16 * u - 16) * N_;
            #pragma unroll
            for (int i = 0; i < 16; ++i) BWD_STEP(i, xp - (size_t)i * N_, true);
        }
        #pragma unroll
        for (int i = 0; i < 16; ++i) BWD_STEP(i, xb, false);   // t = 1039..1024
        #undef BWD_STEP
        *(float4*)(ws_w + b * 256 + l0) = make_float4(a[0], a[1], a[2], a[3]);
    } else {
        // ---------------- FCC chunk: P = prod_s D_t*Ehat over 64 steps --------
        // 32x32x16 MFMA, product kept entirely in registers as B-operand frags.
        // Layouts (gfx950): C/D: col=lane&31, row=(reg&3)+8*(reg>>2)+4*(lane>>5)
        //                   A:   row=lane&31, k = 16*kt + 8*(lane>>5) + j
        //                   B:   col=lane&31, k = 16*kt + 8*(lane>>5) + j
        const int task = (bx < 256) ? (bx * 3 + wid - 1)
                                    : (768 + (bx - 256) * 4 + wid);   // 0..4095
        const int b = task >> 5, k = task & 31;
        const int lane31 = lane & 31, hi = lane >> 5;
        const float* __restrict__ xb = x + (size_t)b * T_ * N_;
        const int t0 = k * 64;
        float* __restrict__ evb = evbuf[wid];

        // A-operand: Ahat[r][kt] = exp(trans[32r+lane31][16kt+8hi+j])
        s16x8 Ahat[2][4];
        float rsum[2];
        #pragma unroll
        for (int r = 0; r < 2; ++r) {
            float rs = 0.f;
            const float* tp = trans + (32 * r + lane31) * N_;
            #pragma unroll
            for (int kt = 0; kt < 4; ++kt) {
                const float* tq = tp + 16 * kt + 8 * hi;
                float4 ta = *(const float4*)tq;
                float4 tb = *(const float4*)(tq + 4);
                float v0 = __expf(ta.x), v1 = __expf(ta.y),
                      v2 = __expf(ta.z), v3 = __expf(ta.w);
                float v4 = __expf(tb.x), v5 = __expf(tb.y),
                      v6 = __expf(tb.z), v7 = __expf(tb.w);
                s16x8 af;
                af[0] = f2bf_rne(v0); af[1] = f2bf_rne(v1);
                af[2] = f2bf_rne(v2); af[3] = f2bf_rne(v3);
                af[4] = f2bf_rne(v4); af[5] = f2bf_rne(v5);
                af[6] = f2bf_rne(v6); af[7] = f2bf_rne(v7);
                rs += ((v0 + v1) + (v2 + v3)) + ((v4 + v5) + (v6 + v7));
                Ahat[r][kt] = af;
            }
            rsum[r] = rs;
        }
        rsum[0] += __shfl_xor(rsum[0], 32);
        rsum[1] += __shfl_xor(rsum[1], 32);
        float rmax = fmaxf(rsum[0], rsum[1]);
        #pragma unroll
        for (int o = 16; o > 0; o >>= 1) rmax = fmaxf(rmax, __shfl_xor(rmax, o));
        const float LS = __logf(rmax);

        // B-operand: identity
        s16x8 Pf[4][2];
        #pragma unroll
        for (int kt = 0; kt < 4; ++kt)
            #pragma unroll
            for (int c = 0; c < 2; ++c) {
                s16x8 pf;
                #pragma unroll
                for (int j = 0; j < 8; ++j)
                    pf[j] = (16 * kt + 8 * hi + j == 32 * c + lane31)
                              ? (short)0x3F80 : (short)0;
                Pf[kt][c] = pf;
            }

        const f32x16 z16 = {};          // zero accumulator seed (kept live)
        f32x16 Y00 = {}, Y01 = {}, Y10 = {}, Y11 = {};
        float xpre[4];
        #pragma unroll
        for (int d = 0; d < 4; ++d)
            xpre[d] = xb[(size_t)(t0 + 1 + d) * N_ + lane];
        float c_acc = 0.f;

        #define MM(af, bf, cf) __builtin_amdgcn_mfma_f32_32x32x16_bf16(af, bf, cf, 0, 0, 0)
        // feedback: Pf'[kt][c] words = {plswap(P0,Q0), plswap(P1,Q1)} of scaled-Y regs
        #define REDIST(kt, c, Yv)                                               \
        {                                                                       \
            unsigned P0 = cvtpk_bf16(Yv[8*((kt)&1) + 0], Yv[8*((kt)&1) + 1]);   \
            unsigned P1 = cvtpk_bf16(Yv[8*((kt)&1) + 2], Yv[8*((kt)&1) + 3]);   \
            unsigned Q0 = cvtpk_bf16(Yv[8*((kt)&1) + 4], Yv[8*((kt)&1) + 5]);   \
            unsigned Q1 = cvtpk_bf16(Yv[8*((kt)&1) + 6], Yv[8*((kt)&1) + 7]);   \
            plswap32(P0, Q0); plswap32(P1, Q1);                                 \
            u32x4 uv; uv[0] = P0; uv[1] = P1; uv[2] = Q0; uv[3] = Q1;           \
            Pf[kt][c] = __builtin_bit_cast(s16x8, uv);                          \
        }

        #pragma unroll 1
        for (int u = 0; u < 16; ++u) {
            #pragma unroll
            for (int i = 0; i < 4; ++i) {
                const int s = 4 * u + i;
                const int t = t0 + 1 + s;
                if (t < T_) {
                    const float xt = xpre[i];
                    int tp2 = t + 4; if (tp2 > T_ - 1) tp2 = T_ - 1;
                    xpre[i] = xb[(size_t)tp2 * N_ + lane];
                    const float gt = __uint_as_float(
                        __builtin_amdgcn_readfirstlane(__float_as_uint(xt))) + LS;
                    c_acc += gt;
                    evb[lane] = __expf(xt - gt);     // ds_write, in-order w/ reads
                    float4 E[2][4];
                    #pragma unroll
                    for (int r = 0; r < 2; ++r)
                        #pragma unroll
                        for (int q = 0; q < 4; ++q)
                            E[r][q] = *(const float4*)&evb[32 * r + 8 * q + 4 * hi];
                    // Y = Ehat * P  (16 mfma, LDS latency hides underneath)
                    Y00 = MM(Ahat[0][0], Pf[0][0], z16);
                    Y01 = MM(Ahat[0][0], Pf[0][1], z16);
                    Y10 = MM(Ahat[1][0], Pf[0][0], z16);
                    Y11 = MM(Ahat[1][0], Pf[0][1], z16);
                    #pragma unroll
                    for (int kt = 1; kt < 4; ++kt) {
                        Y00 = MM(Ahat[0][kt], Pf[kt][0], Y00);
                        Y01 = MM(Ahat[0][kt], Pf[kt][1], Y01);
                        Y10 = MM(Ahat[1][kt], Pf[kt][0], Y10);
                        Y11 = MM(Ahat[1][kt], Pf[kt][1], Y11);
                    }
                    // row scale: row = 32r + 8q + 4hi + m  <->  reg = 4q + m
                    #pragma unroll
                    for (int q = 0; q < 4; ++q) {
                        Y00[4*q+0] *= E[0][q].x; Y00[4*q+1] *= E[0][q].y;
                        Y00[4*q+2] *= E[0][q].z; Y00[4*q+3] *= E[0][q].w;
                        Y01[4*q+0] *= E[0][q].x; Y01[4*q+1] *= E[0][q].y;
                        Y01[4*q+2] *= E[0][q].z; Y01[4*q+3] *= E[0][q].w;
                        Y10[4*q+0] *= E[1][q].x; Y10[4*q+1] *= E[1][q].y;
                        Y10[4*q+2] *= E[1][q].z; Y10[4*q+3] *= E[1][q].w;
                        Y11[4*q+0] *= E[1][q].x; Y11[4*q+1] *= E[1][q].y;
                        Y11[4*q+2] *= E[1][q].z; Y11[4*q+3] *= E[1][q].w;
                    }
                    // in-register feedback into B-operand fragments
                    REDIST(0, 0, Y00); REDIST(0, 1, Y01);
                    REDIST(1, 0, Y00); REDIST(1, 1, Y01);
                    REDIST(2, 0, Y10); REDIST(2, 1, Y11);
                    REDIST(3, 0, Y10); REDIST(3, 1, Y11);
                }
            }
        }
        #undef REDIST
        #undef MM

        // store P[m][n] bf16: row = 32r + 8q + 4hi + m, col = 32c + lane31
        unsigned short* dst = ws_R + (size_t)(b * 32 + k) * 4096;
        #pragma unroll
        for (int q = 0; q < 4; ++q)
            #pragma unroll
            for (int m = 0; m < 4; ++m) {
                const int reg = 4 * q + m;
                const int rw  = 8 * q + 4 * hi + m;
                dst[(rw     ) * 64 + lane31     ] = (unsigned short)f2bf_rne(Y00[reg]);
                dst[(rw     ) * 64 + 32 + lane31] = (unsigned short)f2bf_rne(Y01[reg]);
                dst[(32 + rw) * 64 + lane31     ] = (unsigned short)f2bf_rne(Y10[reg]);
                dst[(32 + rw) * 64 + 32 + lane31] = (unsigned short)f2bf_rne(Y11[reg]);
            }
        if (lane == 0) ws_c[b * 32 + k] = c_acc;
    }
}

// Kernel 2: wave0 = fcc chunk combine (LDS-staged, depth-2 register prefetch,
// per-iteration max-rescale); wave1 = fwd/bwd fac combine. One block per batch.
__global__ __launch_bounds__(128) void asg_k2(
    const float* __restrict__ x,
    const float* __restrict__ ws_c,
    const unsigned short* __restrict__ ws_R,
    const float* __restrict__ ws_v,
    const float* __restrict__ ws_w,
    float* __restrict__ out)
{
    __shared__ short rb[2][N_ * PITCH];
    __shared__ __align__(16) float sa[N_];
    __shared__ float sres[2];
    const int b = blockIdx.x, tid = threadIdx.x, lane = tid & 63;

    if (tid < 64) {
        float a0 = x[(size_t)b * T_ * N_ + lane];
        float m0 = a0;
        #pragma unroll
        for (int o = 32; o > 0; o >>= 1) m0 = fmaxf(m0, __shfl_xor(m0, o));
        float  a  = __expf(a0 - m0);
        double Cd = (double)m0;

        const unsigned short* Rb = ws_R + (size_t)b * 32 * 4096;
        const int frow = (lane >> 3), fcol = (lane & 7) * 8;  // staging lane slot
        // preload chunk 0 -> buf 0 (coalesced b128)
        {
            #pragma unroll
            for (int q = 0; q < 8; ++q) {
                s16x8 v = *(const s16x8*)(Rb + lane * 8 + 512 * q);
                *(s16x8*)&rb[0][(frow + 8 * q) * PITCH + fcol] = v;
            }
        }
        // issue chunk-1 loads
        s16x8 nvA[8], nvB[8];
        #pragma unroll
        for (int q = 0; q < 8; ++q)
            nvA[q] = *(const s16x8*)(Rb + (size_t)4096 + lane * 8 + 512 * q);

        // one chunk application: a <- normalize((R_kk)·a), Cd += scales
        auto k2_step = [&](int kk, int bufi) {
            sa[lane] = a;
            float4 sav[16];
            #pragma unroll
            for (int q = 0; q < 16; ++q) sav[q] = ((const float4*)sa)[q];
            float acc4[4] = {0.f, 0.f, 0.f, 0.f};
            #pragma unroll
            for (int u = 0; u < 8; ++u) {
                s16x8 rr = *(const s16x8*)&rb[bufi][lane * PITCH + u * 8];
                const float4 s0 = sav[2 * u], s1 = sav[2 * u + 1];
                acc4[0] = fmaf(bf2f((unsigned short)rr[0]), s0.x, acc4[0]);
                acc4[1] = fmaf(bf2f((unsigned short)rr[1]), s0.y, acc4[1]);
                acc4[2] = fmaf(bf2f((unsigned short)rr[2]), s0.z, acc4[2]);
                acc4[3] = fmaf(bf2f((unsigned short)rr[3]), s0.w, acc4[3]);
                acc4[0] = fmaf(bf2f((unsigned short)rr[4]), s1.x, acc4[0]);
                acc4[1] = fmaf(bf2f((unsigned short)rr[5]), s1.y, acc4[1]);
                acc4[2] = fmaf(bf2f((unsigned short)rr[6]), s1.z, acc4[2]);
                acc4[3] = fmaf(bf2f((unsigned short)rr[7]), s1.w, acc4[3]);
            }
            float acc = (acc4[0] + acc4[1]) + (acc4[2] + acc4[3]);
            float rm = acc;
            #pragma unroll
            for (int o = 32; o > 0; o >>= 1) rm = fmaxf(rm, __shfl_xor(rm, o));
            a = acc / rm;
            Cd += (double)(__logf(rm) + ws_c[b * 32 + kk]);
        };

        for (int kk = 0; kk < 32; kk += 2) {
            // even iter: prefetch chunk kk+2 -> nvB, compute rb[kk&1], stage nvA
            const int kA = (kk + 2 < 32) ? kk + 2 : 31;
            #pragma unroll
            for (int q = 0; q < 8; ++q)
                nvB[q] = *(const s16x8*)(Rb + (size_t)kA * 4096 + lane * 8 + 512 * q);
            k2_step(kk, kk & 1);
            #pragma unroll
            for (int q = 0; q < 8; ++q)
                *(s16x8*)&rb[(kk + 1) & 1][(frow + 8 * q) * PITCH + fcol] = nvA[q];
            // odd iter: prefetch chunk kk+3 -> nvA, compute rb[(kk+1)&1], stage nvB
            const int kB = (kk + 3 < 32) ? kk + 3 : 31;
            #pragma unroll
            for (int q = 0; q < 8; ++q)
                nvA[q] = *(const s16x8*)(Rb + (size_t)kB * 4096 + lane * 8 + 512 * q);
            k2_step(kk + 1, (kk + 1) & 1);
            #pragma unroll
            for (int q = 0; q < 8; ++q)
                *(s16x8*)&rb[kk & 1][(frow + 8 * q) * PITCH + fcol] = nvB[q];
        }
        float ssum = a;
        #pragma unroll
        for (int o = 32; o > 0; o >>= 1) ssum += __shfl_xor(ssum, o);
        if (lane == 0) sres[0] = (float)(Cd + (double)__logf(ssum));
    } else {
        // fac combine: F = ln-domain lse over 256 cells of (alpha+beta), log2 inputs
        float4 v4 = ((const float4*)(ws_v + b * 256))[lane];
        float4 w4 = ((const float4*)(ws_w + b * 256))[lane];
        const float s0 = v4.x + w4.x, s1 = v4.y + w4.y,
                    s2 = v4.z + w4.z, s3 = v4.w + w4.w;
        float m = fmaxf(fmaxf(s0, s1), fmaxf(s2, s3));
        #pragma unroll
        for (int o = 32; o > 0; o >>= 1) m = fmaxf(m, __shfl_xor(m, o));
        float sum = __builtin_amdgcn_exp2f(s0 - m) + __builtin_amdgcn_exp2f(s1 - m)
                  + __builtin_amdgcn_exp2f(s2 - m) + __builtin_amdgcn_exp2f(s3 - m);
        #pragma unroll
        for (int o = 32; o > 0; o >>= 1) sum += __shfl_xor(sum, o);
        if (lane == 0) sres[1] = (m + __builtin_amdgcn_logf(sum)) * LN2;
    }
    __syncthreads();
    if (tid == 0) out[b] = sres[0] - sres[1];
}

extern "C" void kernel_launch(void* const* d_in, const int* in_sizes, int n_in,
                              void* d_out, int out_size, void* d_ws, size_t ws_size,
                              hipStream_t stream) {
    (void)in_sizes; (void)n_in; (void)out_size; (void)ws_size;
    const float* xin    = (const float*)d_in[0];
    const int*   target = (const int*)  d_in[1];
    const int*   tsz    = (const int*)  d_in[2];
    const float* trans  = (const float*)d_in[3];
    float* out = (float*)d_out;

    float*          ws_c = (float*)d_ws;                                    // 16 KB
    unsigned short* ws_R = (unsigned short*)((char*)d_ws + 16384);          // 33.55 MB
    float*          ws_v = (float*)((char*)d_ws + 16384 + 33554432);        // 128 KB
    float*          ws_w = (float*)((char*)d_ws + 16384 + 33554432 + 131072);

    // blocks 0..255: 1 fac wave + 3 fcc waves; blocks 256..1087: 4 fcc waves
    asg_k1<<<dim3(1088), dim3(256), 0, stream>>>(xin, target, tsz, trans,
                                                 ws_c, ws_R, ws_v, ws_w);
    asg_k2<<<dim3(B_), dim3(128), 0, stream>>>(xin, ws_c, ws_R, ws_v, ws_w, out);
}

// Round 5
// 245.399 us; speedup vs baseline: 1.3733x; 1.2914x over previous
//
#include <hip/hip_runtime.h>

#define B_ 128
#define T_ 2048
#define N_ 64
#define L_ 256
#define NEGV (-1e30f)
#define PITCH 72   // shorts per LDS row (64 + 8 pad) for k2 staging
#define LOG2E 1.4426950408889634f
#define LN2   0.6931471805599453f

typedef short  s16x4 __attribute__((ext_vector_type(4)));
typedef short  s16x8 __attribute__((ext_vector_type(8)));
typedef float  f32x4 __attribute__((ext_vector_type(4)));
typedef float  f32x16 __attribute__((ext_vector_type(16)));
typedef unsigned int u32x2 __attribute__((ext_vector_type(2)));
typedef unsigned int u32x4 __attribute__((ext_vector_type(4)));

__device__ __forceinline__ short f2bf_rne(float f) {
    unsigned u = __float_as_uint(f);
    unsigned r = (u + 0x7FFFu + ((u >> 16) & 1u)) >> 16;
    return (short)r;
}
__device__ __forceinline__ float bf2f(unsigned short u) {
    return __uint_as_float(((unsigned)u) << 16);
}
__device__ __forceinline__ float bperm(int byteaddr, float v) {
    return __int_as_float(__builtin_amdgcn_ds_bpermute(byteaddr, __float_as_int(v)));
}
__device__ __forceinline__ float ex2f(float x) { return __builtin_amdgcn_exp2f(x); }
__device__ __forceinline__ float lg2f(float x) { return __builtin_amdgcn_logf(x); }
// pack 2 f32 -> 2 bf16 (RNE) in one u32
__device__ __forceinline__ unsigned cvtpk_bf16(float lo, float hi) {
    unsigned r;
    asm("v_cvt_pk_bf16_f32 %0, %1, %2" : "=v"(r) : "v"(lo), "v"(hi));
    return r;
}
// swap upper 32 lanes of x with lower 32 lanes of y
__device__ __forceinline__ void plswap32(unsigned &x, unsigned &y) {
    asm("v_permlane32_swap_b32 %0, %1" : "+v"(x), "+v"(y));
}

// Kernel 1: W = bx*4+wid. W<128 fwd-FAC, W<256 bwd-FAC (packed: blocks 0..63,
// 2 FAC waves/SIMD), else FCC chunk builders. FAC runs the banded recurrence
// in EXP domain within 8-step blocks (block-local max anchor, exact log2
// state at block boundaries) -> ~3x fewer issue cycles than log-domain lse.
__global__ __launch_bounds__(256, 2) void asg_k1(
    const float* __restrict__ x,       // (B,T,N)
    const int*   __restrict__ target,  // (B,L)
    const int*   __restrict__ tsize,   // (B,)
    const float* __restrict__ trans,   // (N,N)
    float* __restrict__ ws_c,          // (B,32) chunk log-scales
    unsigned short* __restrict__ ws_R, // (B,32,64,64) bf16 chunk matrices [m][n]
    float* __restrict__ ws_v,          // (B,256) alpha_1023 (log2 domain)
    float* __restrict__ ws_w)          // (B,256) beta_1023  (log2 domain)
{
    __shared__ float evbuf[4][N_];     // per-wave ev broadcast buffer (FCC)
    const int wid  = threadIdx.x >> 6;
    const int lane = threadIdx.x & 63;
    const int W    = blockIdx.x * 4 + wid;

    if (W < 128) {
        // ---------------- FAC forward: alpha_0 .. alpha_1023 ----------------
        const int b  = W;
        const float* __restrict__ xb = x + (size_t)b * T_ * N_;
        const int l0 = lane * 4;
        int tga[4];
        float Sx0, Sx1, Sx2, Sx3, Mx0, Mx1, Mx2, Mx3;
        float al0, al1, al2, al3;
        {
            const int t0v = target[b * L_ + l0 + 0];
            const int t1v = target[b * L_ + l0 + 1];
            const int t2v = target[b * L_ + l0 + 2];
            const int t3v = target[b * L_ + l0 + 3];
            tga[0] = t0v << 2; tga[1] = t1v << 2;
            tga[2] = t2v << 2; tga[3] = t3v << 2;
            Sx0 = ex2f(trans[t0v * N_ + t0v] * LOG2E);
            Sx1 = ex2f(trans[t1v * N_ + t1v] * LOG2E);
            Sx2 = ex2f(trans[t2v * N_ + t2v] * LOG2E);
            Sx3 = ex2f(trans[t3v * N_ + t3v] * LOG2E);
            Mx1 = ex2f(trans[t1v * N_ + t0v] * LOG2E);
            Mx2 = ex2f(trans[t2v * N_ + t1v] * LOG2E);
            Mx3 = ex2f(trans[t3v * N_ + t2v] * LOG2E);
            const int tRm = target[b * L_ + ((l0 >= 1) ? l0 - 1 : 0)];
            Mx0 = ex2f(trans[t0v * N_ + tRm] * LOG2E);
            al0 = (lane == 0) ? xb[t0v] * LOG2E : NEGV;
            al1 = NEGV; al2 = NEGV; al3 = NEGV;
        }
        const int upA = ((lane == 0) ? 0 : lane - 1) << 2;

        float xr[16];
        #pragma unroll
        for (int i = 0; i < 16; ++i) xr[i] = xb[(size_t)(1 + i) * N_ + lane];
        float exn = ex2f(xr[0] * LOG2E);
        float e0 = bperm(tga[0], exn), e1 = bperm(tga[1], exn),
              e2 = bperm(tga[2], exn), e3 = bperm(tga[3], exn);

        float A0, A1, A2, A3, mloc, cfm0;

        #define FPRO()                                                          \
        {                                                                       \
            float bpm_ = bperm(upA, al3);                                       \
            float ml_ = fmaxf(fmaxf(al0, al1), fmaxf(al2, al3));                \
            ml_ = fmaxf(ml_, bpm_);                                             \
            float mpl_ = bperm(upA, ml_);                                       \
            float cf_ = ex2f(fminf(mpl_ - ml_, 120.f));                         \
            cfm0 = (lane == 0) ? 0.f : cf_ * Mx0;                               \
            mloc = ml_;                                                         \
            A0 = ex2f(al0 - ml_); A1 = ex2f(al1 - ml_);                         \
            A2 = ex2f(al2 - ml_); A3 = ex2f(al3 - ml_);                         \
        }
        #define FEPI()                                                          \
        {                                                                       \
            al0 = fmaxf(lg2f(A0) + mloc, NEGV);                                 \
            al1 = fmaxf(lg2f(A1) + mloc, NEGV);                                 \
            al2 = fmaxf(lg2f(A2) + mloc, NEGV);                                 \
            al3 = fmaxf(lg2f(A3) + mloc, NEGV);                                 \
        }
        #define FSTEP(i, rp, RF)                                                \
        {                                                                       \
            float A3bp = bperm(upA, A3);                                        \
            const float c0 = e0, c1 = e1, c2 = e2, c3 = e3;                     \
            float ex2_ = ex2f(xr[((i) + 1) & 15] * LOG2E);                      \
            e0 = bperm(tga[0], ex2_); e1 = bperm(tga[1], ex2_);                 \
            e2 = bperm(tga[2], ex2_); e3 = bperm(tga[3], ex2_);                 \
            if (RF) xr[i] = (rp)[lane];                                         \
            const float n0 = c0 * fmaf(A0, Sx0, A3bp * cfm0);                   \
            const float n1 = c1 * fmaf(A1, Sx1, A0 * Mx1);                      \
            const float n2 = c2 * fmaf(A2, Sx2, A1 * Mx2);                      \
            const float n3 = c3 * fmaf(A3, Sx3, A2 * Mx3);                      \
            A0 = n0; A1 = n1; A2 = n2; A3 = n3;                                 \
        }

        for (int u = 0; u < 63; ++u) {                  // t = 1..1008
            const float* __restrict__ xp = xb + (size_t)(16 * u + 17) * N_;
            #pragma unroll
            for (int i = 0; i < 16; ++i) {
                if (i == 0 || i == 8) FPRO()
                FSTEP(i, xp + i * N_, true)
                if (i == 7 || i == 15) FEPI()
            }
        }
        #pragma unroll
        for (int i = 0; i < 15; ++i) {                  // t = 1009..1023
            if (i == 0 || i == 8) FPRO()
            FSTEP(i, xb, false)
            if (i == 7 || i == 14) FEPI()
        }
        #undef FPRO
        #undef FEPI
        #undef FSTEP
        *(float4*)(ws_v + b * 256 + l0) = make_float4(al0, al1, al2, al3);
    } else if (W < 256) {
        // ---------------- FAC backward: beta_2047 .. beta_1023 ----------------
        const int b  = W - 128;
        const float* __restrict__ xb = x + (size_t)b * T_ * N_;
        const int l0 = lane * 4;
        const int lt = tsize[b] - 1;
        int tga[4], tgR;
        float Sx0, Sx1, Sx2, Sx3, Mx1, Mx2, Mx3, MRx;
        float al0, al1, al2, al3;
        {
            const int t0v = target[b * L_ + l0 + 0];
            const int t1v = target[b * L_ + l0 + 1];
            const int t2v = target[b * L_ + l0 + 2];
            const int t3v = target[b * L_ + l0 + 3];
            tga[0] = t0v << 2; tga[1] = t1v << 2;
            tga[2] = t2v << 2; tga[3] = t3v << 2;
            Sx0 = ex2f(trans[t0v * N_ + t0v] * LOG2E);
            Sx1 = ex2f(trans[t1v * N_ + t1v] * LOG2E);
            Sx2 = ex2f(trans[t2v * N_ + t2v] * LOG2E);
            Sx3 = ex2f(trans[t3v * N_ + t3v] * LOG2E);
            Mx1 = ex2f(trans[t1v * N_ + t0v] * LOG2E);
            Mx2 = ex2f(trans[t2v * N_ + t1v] * LOG2E);
            Mx3 = ex2f(trans[t3v * N_ + t2v] * LOG2E);
            const int tR = target[b * L_ + ((l0 + 4 <= L_ - 1) ? l0 + 4 : L_ - 1)];
            tgR = tR << 2;
            MRx = ex2f(trans[tR * N_ + t3v] * LOG2E);   // move l0+3 -> l0+4
            al0 = (l0 + 0 == lt) ? 0.f : NEGV;
            al1 = (l0 + 1 == lt) ? 0.f : NEGV;
            al2 = (l0 + 2 == lt) ? 0.f : NEGV;
            al3 = (l0 + 3 == lt) ? 0.f : NEGV;
        }
        const int dnA = ((lane == 63) ? 63 : lane + 1) << 2;

        float xr[16];
        #pragma unroll
        for (int i = 0; i < 16; ++i) xr[i] = xb[(size_t)(2047 - i) * N_ + lane];
        float exn = ex2f(xr[0] * LOG2E);
        float e0 = bperm(tga[0], exn), e1 = bperm(tga[1], exn),
              e2 = bperm(tga[2], exn), e3 = bperm(tga[3], exn),
              eR = bperm(tgR, exn);

        float A0, A1, A2, A3, mloc, cfm;

        #define BPRO()                                                          \
        {                                                                       \
            float bpm_ = bperm(dnA, al0);                                       \
            float ml_ = fmaxf(fmaxf(al0, al1), fmaxf(al2, al3));                \
            ml_ = fmaxf(ml_, bpm_);                                             \
            float mpl_ = bperm(dnA, ml_);                                       \
            float cf_ = ex2f(fminf(mpl_ - ml_, 120.f));                         \
            cfm = (lane == 63) ? 0.f : cf_ * MRx;                               \
            mloc = ml_;                                                         \
            A0 = ex2f(al0 - ml_); A1 = ex2f(al1 - ml_);                         \
            A2 = ex2f(al2 - ml_); A3 = ex2f(al3 - ml_);                         \
        }
        #define BEPI()                                                          \
        {                                                                       \
            al0 = fmaxf(lg2f(A0) + mloc, NEGV);                                 \
            al1 = fmaxf(lg2f(A1) + mloc, NEGV);                                 \
            al2 = fmaxf(lg2f(A2) + mloc, NEGV);                                 \
            al3 = fmaxf(lg2f(A3) + mloc, NEGV);                                 \
        }
        #define BSTEP(i, rp, RF)                                                \
        {                                                                       \
            float A0bp = bperm(dnA, A0);                                        \
            const float c0 = e0, c1 = e1, c2 = e2, c3 = e3, cR = eR;            \
            float ex2_ = ex2f(xr[((i) + 1) & 15] * LOG2E);                      \
            e0 = bperm(tga[0], ex2_); e1 = bperm(tga[1], ex2_);                 \
            e2 = bperm(tga[2], ex2_); e3 = bperm(tga[3], ex2_);                 \
            eR = bperm(tgR, ex2_);                                              \
            if (RF) xr[i] = (rp)[lane];                                         \
            const float T0 = A0 * c0, T1 = A1 * c1, T2 = A2 * c2, T3 = A3 * c3; \
            const float n0 = fmaf(T1, Mx1, T0 * Sx0);                           \
            const float n1 = fmaf(T2, Mx2, T1 * Sx1);                           \
            const float n2 = fmaf(T3, Mx3, T2 * Sx2);                           \
            const float n3 = fmaf(A0bp * cR, cfm, T3 * Sx3);                    \
            A0 = n0; A1 = n1; A2 = n2; A3 = n3;                                 \
        }

        for (int u = 0; u < 63; ++u) {                  // t = 2047..1040
            const float* __restrict__ xp = xb + (size_t)(2047 - 16 * u - 16) * N_;
            #pragma unroll
            for (int i = 0; i < 16; ++i) {
                if (i == 0 || i == 8) BPRO()
                BSTEP(i, xp - (size_t)i * N_, true)
                if (i == 7 || i == 15) BEPI()
            }
        }
        #pragma unroll
        for (int i = 0; i < 16; ++i) {                  // t = 1039..1024
            if (i == 0 || i == 8) BPRO()
            BSTEP(i, xb, false)
            if (i == 7 || i == 15) BEPI()
        }
        #undef BPRO
        #undef BEPI
        #undef BSTEP
        *(float4*)(ws_w + b * 256 + l0) = make_float4(al0, al1, al2, al3);
    } else {
        // ---------------- FCC chunk: P = prod_s D_t*Ehat over 64 steps --------
        // 32x32x16 MFMA, product kept entirely in registers as B-operand frags.
        // Layouts (gfx950): C/D: col=lane&31, row=(reg&3)+8*(reg>>2)+4*(lane>>5)
        //                   A:   row=lane&31, k = 16*kt + 8*(lane>>5) + j
        //                   B:   col=lane&31, k = 16*kt + 8*(lane>>5) + j
        const int task = W - 256;              // 0..4095
        const int b = task >> 5, k = task & 31;
        const int lane31 = lane & 31, hi = lane >> 5;
        const float* __restrict__ xb = x + (size_t)b * T_ * N_;
        const int t0 = k * 64;
        float* __restrict__ evb = evbuf[wid];

        // A-operand: Ahat[r][kt] = exp(trans[32r+lane31][16kt+8hi+j])
        s16x8 Ahat[2][4];
        float rsum[2];
        #pragma unroll
        for (int r = 0; r < 2; ++r) {
            float rs = 0.f;
            const float* tp = trans + (32 * r + lane31) * N_;
            #pragma unroll
            for (int kt = 0; kt < 4; ++kt) {
                const float* tq = tp + 16 * kt + 8 * hi;
                float4 ta = *(const float4*)tq;
                float4 tb = *(const float4*)(tq + 4);
                float v0 = __expf(ta.x), v1 = __expf(ta.y),
                      v2 = __expf(ta.z), v3 = __expf(ta.w);
                float v4 = __expf(tb.x), v5 = __expf(tb.y),
                      v6 = __expf(tb.z), v7 = __expf(tb.w);
                s16x8 af;
                af[0] = f2bf_rne(v0); af[1] = f2bf_rne(v1);
                af[2] = f2bf_rne(v2); af[3] = f2bf_rne(v3);
                af[4] = f2bf_rne(v4); af[5] = f2bf_rne(v5);
                af[6] = f2bf_rne(v6); af[7] = f2bf_rne(v7);
                rs += ((v0 + v1) + (v2 + v3)) + ((v4 + v5) + (v6 + v7));
                Ahat[r][kt] = af;
            }
            rsum[r] = rs;
        }
        rsum[0] += __shfl_xor(rsum[0], 32);
        rsum[1] += __shfl_xor(rsum[1], 32);
        float rmax = fmaxf(rsum[0], rsum[1]);
        #pragma unroll
        for (int o = 16; o > 0; o >>= 1) rmax = fmaxf(rmax, __shfl_xor(rmax, o));
        const float LS = __logf(rmax);

        // B-operand: identity
        s16x8 Pf[4][2];
        #pragma unroll
        for (int kt = 0; kt < 4; ++kt)
            #pragma unroll
            for (int c = 0; c < 2; ++c) {
                s16x8 pf;
                #pragma unroll
                for (int j = 0; j < 8; ++j)
                    pf[j] = (16 * kt + 8 * hi + j == 32 * c + lane31)
                              ? (short)0x3F80 : (short)0;
                Pf[kt][c] = pf;
            }

        const f32x16 z16 = {};          // zero accumulator seed (kept live)
        f32x16 Y00 = {}, Y01 = {}, Y10 = {}, Y11 = {};
        float xpre[4];
        #pragma unroll
        for (int d = 0; d < 4; ++d)
            xpre[d] = xb[(size_t)(t0 + 1 + d) * N_ + lane];
        float c_acc = 0.f;

        #define MM(af, bf, cf) __builtin_amdgcn_mfma_f32_32x32x16_bf16(af, bf, cf, 0, 0, 0)
        // feedback: Pf'[kt][c] words = {plswap(P0,Q0), plswap(P1,Q1)} of scaled-Y regs
        #define REDIST(kt, c, Yv)                                               \
        {                                                                       \
            unsigned P0 = cvtpk_bf16(Yv[8*((kt)&1) + 0], Yv[8*((kt)&1) + 1]);   \
            unsigned P1 = cvtpk_bf16(Yv[8*((kt)&1) + 2], Yv[8*((kt)&1) + 3]);   \
            unsigned Q0 = cvtpk_bf16(Yv[8*((kt)&1) + 4], Yv[8*((kt)&1) + 5]);   \
            unsigned Q1 = cvtpk_bf16(Yv[8*((kt)&1) + 6], Yv[8*((kt)&1) + 7]);   \
            plswap32(P0, Q0); plswap32(P1, Q1);                                 \
            u32x4 uv; uv[0] = P0; uv[1] = P1; uv[2] = Q0; uv[3] = Q1;           \
            Pf[kt][c] = __builtin_bit_cast(s16x8, uv);                          \
        }

        #pragma unroll 1
        for (int u = 0; u < 16; ++u) {
            #pragma unroll
            for (int i = 0; i < 4; ++i) {
                const int s = 4 * u + i;
                const int t = t0 + 1 + s;
                if (t < T_) {
                    const float xt = xpre[i];
                    int tp2 = t + 4; if (tp2 > T_ - 1) tp2 = T_ - 1;
                    xpre[i] = xb[(size_t)tp2 * N_ + lane];
                    const float gt = __uint_as_float(
                        __builtin_amdgcn_readfirstlane(__float_as_uint(xt))) + LS;
                    c_acc += gt;
                    evb[lane] = __expf(xt - gt);     // ds_write, in-order w/ reads
                    float4 E[2][4];
                    #pragma unroll
                    for (int r = 0; r < 2; ++r)
                        #pragma unroll
                        for (int q = 0; q < 4; ++q)
                            E[r][q] = *(const float4*)&evb[32 * r + 8 * q + 4 * hi];
                    // Y = Ehat * P  (16 mfma, LDS latency hides underneath)
                    Y00 = MM(Ahat[0][0], Pf[0][0], z16);
                    Y01 = MM(Ahat[0][0], Pf[0][1], z16);
                    Y10 = MM(Ahat[1][0], Pf[0][0], z16);
                    Y11 = MM(Ahat[1][0], Pf[0][1], z16);
                    #pragma unroll
                    for (int kt = 1; kt < 4; ++kt) {
                        Y00 = MM(Ahat[0][kt], Pf[kt][0], Y00);
                        Y01 = MM(Ahat[0][kt], Pf[kt][1], Y01);
                        Y10 = MM(Ahat[1][kt], Pf[kt][0], Y10);
                        Y11 = MM(Ahat[1][kt], Pf[kt][1], Y11);
                    }
                    // row scale: row = 32r + 8q + 4hi + m  <->  reg = 4q + m
                    #pragma unroll
                    for (int q = 0; q < 4; ++q) {
                        Y00[4*q+0] *= E[0][q].x; Y00[4*q+1] *= E[0][q].y;
                        Y00[4*q+2] *= E[0][q].z; Y00[4*q+3] *= E[0][q].w;
                        Y01[4*q+0] *= E[0][q].x; Y01[4*q+1] *= E[0][q].y;
                        Y01[4*q+2] *= E[0][q].z; Y01[4*q+3] *= E[0][q].w;
                        Y10[4*q+0] *= E[1][q].x; Y10[4*q+1] *= E[1][q].y;
                        Y10[4*q+2] *= E[1][q].z; Y10[4*q+3] *= E[1][q].w;
                        Y11[4*q+0] *= E[1][q].x; Y11[4*q+1] *= E[1][q].y;
                        Y11[4*q+2] *= E[1][q].z; Y11[4*q+3] *= E[1][q].w;
                    }
                    // in-register feedback into B-operand fragments
                    REDIST(0, 0, Y00); REDIST(0, 1, Y01);
                    REDIST(1, 0, Y00); REDIST(1, 1, Y01);
                    REDIST(2, 0, Y10); REDIST(2, 1, Y11);
                    REDIST(3, 0, Y10); REDIST(3, 1, Y11);
                }
            }
        }
        #undef REDIST
        #undef MM

        // store P[m][n] bf16: row = 32r + 8q + 4hi + m, col = 32c + lane31
        unsigned short* dst = ws_R + (size_t)(b * 32 + k) * 4096;
        #pragma unroll
        for (int q = 0; q < 4; ++q)
            #pragma unroll
            for (int m = 0; m < 4; ++m) {
                const int reg = 4 * q + m;
                const int rw  = 8 * q + 4 * hi + m;
                dst[(rw     ) * 64 + lane31     ] = (unsigned short)f2bf_rne(Y00[reg]);
                dst[(rw     ) * 64 + 32 + lane31] = (unsigned short)f2bf_rne(Y01[reg]);
                dst[(32 + rw) * 64 + lane31     ] = (unsigned short)f2bf_rne(Y10[reg]);
                dst[(32 + rw) * 64 + 32 + lane31] = (unsigned short)f2bf_rne(Y11[reg]);
            }
        if (lane == 0) ws_c[b * 32 + k] = c_acc;
    }
}

// Kernel 2: wave0 = fcc chunk combine (LDS-staged, depth-2 register prefetch,
// per-iteration max-rescale); wave1 = fwd/bwd fac combine. One block per batch.
__global__ __launch_bounds__(128) void asg_k2(
    const float* __restrict__ x,
    const float* __restrict__ ws_c,
    const unsigned short* __restrict__ ws_R,
    const float* __restrict__ ws_v,
    const float* __restrict__ ws_w,
    float* __restrict__ out)
{
    __shared__ short rb[2][N_ * PITCH];
    __shared__ __align__(16) float sa[N_];
    __shared__ float sres[2];
    const int b = blockIdx.x, tid = threadIdx.x, lane = tid & 63;

    if (tid < 64) {
        float a0 = x[(size_t)b * T_ * N_ + lane];
        float m0 = a0;
        #pragma unroll
        for (int o = 32; o > 0; o >>= 1) m0 = fmaxf(m0, __shfl_xor(m0, o));
        float  a  = __expf(a0 - m0);
        double Cd = (double)m0;

        const unsigned short* Rb = ws_R + (size_t)b * 32 * 4096;
        const int frow = (lane >> 3), fcol = (lane & 7) * 8;  // staging lane slot
        // preload chunk 0 -> buf 0 (coalesced b128)
        {
            #pragma unroll
            for (int q = 0; q < 8; ++q) {
                s16x8 v = *(const s16x8*)(Rb + lane * 8 + 512 * q);
                *(s16x8*)&rb[0][(frow + 8 * q) * PITCH + fcol] = v;
            }
        }
        // issue chunk-1 loads
        s16x8 nvA[8], nvB[8];
        #pragma unroll
        for (int q = 0; q < 8; ++q)
            nvA[q] = *(const s16x8*)(Rb + (size_t)4096 + lane * 8 + 512 * q);

        // one chunk application: a <- normalize((R_kk)·a), Cd += scales
        auto k2_step = [&](int kk, int bufi) {
            sa[lane] = a;
            float4 sav[16];
            #pragma unroll
            for (int q = 0; q < 16; ++q) sav[q] = ((const float4*)sa)[q];
            float acc4[4] = {0.f, 0.f, 0.f, 0.f};
            #pragma unroll
            for (int u = 0; u < 8; ++u) {
                s16x8 rr = *(const s16x8*)&rb[bufi][lane * PITCH + u * 8];
                const float4 s0 = sav[2 * u], s1 = sav[2 * u + 1];
                acc4[0] = fmaf(bf2f((unsigned short)rr[0]), s0.x, acc4[0]);
                acc4[1] = fmaf(bf2f((unsigned short)rr[1]), s0.y, acc4[1]);
                acc4[2] = fmaf(bf2f((unsigned short)rr[2]), s0.z, acc4[2]);
                acc4[3] = fmaf(bf2f((unsigned short)rr[3]), s0.w, acc4[3]);
                acc4[0] = fmaf(bf2f((unsigned short)rr[4]), s1.x, acc4[0]);
                acc4[1] = fmaf(bf2f((unsigned short)rr[5]), s1.y, acc4[1]);
                acc4[2] = fmaf(bf2f((unsigned short)rr[6]), s1.z, acc4[2]);
                acc4[3] = fmaf(bf2f((unsigned short)rr[7]), s1.w, acc4[3]);
            }
            float acc = (acc4[0] + acc4[1]) + (acc4[2] + acc4[3]);
            float rm = acc;
            #pragma unroll
            for (int o = 32; o > 0; o >>= 1) rm = fmaxf(rm, __shfl_xor(rm, o));
            a = acc / rm;
            Cd += (double)(__logf(rm) + ws_c[b * 32 + kk]);
        };

        for (int kk = 0; kk < 32; kk += 2) {
            // even iter: prefetch chunk kk+2 -> nvB, compute rb[kk&1], stage nvA
            const int kA = (kk + 2 < 32) ? kk + 2 : 31;
            #pragma unroll
            for (int q = 0; q < 8; ++q)
                nvB[q] = *(const s16x8*)(Rb + (size_t)kA * 4096 + lane * 8 + 512 * q);
            k2_step(kk, kk & 1);
            #pragma unroll
            for (int q = 0; q < 8; ++q)
                *(s16x8*)&rb[(kk + 1) & 1][(frow + 8 * q) * PITCH + fcol] = nvA[q];
            // odd iter: prefetch chunk kk+3 -> nvA, compute rb[(kk+1)&1], stage nvB
            const int kB = (kk + 3 < 32) ? kk + 3 : 31;
            #pragma unroll
            for (int q = 0; q < 8; ++q)
                nvA[q] = *(const s16x8*)(Rb + (size_t)kB * 4096 + lane * 8 + 512 * q);
            k2_step(kk + 1, (kk + 1) & 1);
            #pragma unroll
            for (int q = 0; q < 8; ++q)
                *(s16x8*)&rb[kk & 1][(frow + 8 * q) * PITCH + fcol] = nvB[q];
        }
        float ssum = a;
        #pragma unroll
        for (int o = 32; o > 0; o >>= 1) ssum += __shfl_xor(ssum, o);
        if (lane == 0) sres[0] = (float)(Cd + (double)__logf(ssum));
    } else {
        // fac combine: F = ln-domain lse over 256 cells of (alpha+beta), log2 inputs
        float4 v4 = ((const float4*)(ws_v + b * 256))[lane];
        float4 w4 = ((const float4*)(ws_w + b * 256))[lane];
        const float s0 = v4.x + w4.x, s1 = v4.y + w4.y,
                    s2 = v4.z + w4.z, s3 = v4.w + w4.w;
        float m = fmaxf(fmaxf(s0, s1), fmaxf(s2, s3));
        #pragma unroll
        for (int o = 32; o > 0; o >>= 1) m = fmaxf(m, __shfl_xor(m, o));
        float sum = __builtin_amdgcn_exp2f(s0 - m) + __builtin_amdgcn_exp2f(s1 - m)
                  + __builtin_amdgcn_exp2f(s2 - m) + __builtin_amdgcn_exp2f(s3 - m);
        #pragma unroll
        for (int o = 32; o > 0; o >>= 1) sum += __shfl_xor(sum, o);
        if (lane == 0) sres[1] = (m + __builtin_amdgcn_logf(sum)) * LN2;
    }
    __syncthreads();
    if (tid == 0) out[b] = sres[0] - sres[1];
}

extern "C" void kernel_launch(void* const* d_in, const int* in_sizes, int n_in,
                              void* d_out, int out_size, void* d_ws, size_t ws_size,
                              hipStream_t stream) {
    (void)in_sizes; (void)n_in; (void)out_size; (void)ws_size;
    const float* xin    = (const float*)d_in[0];
    const int*   target = (const int*)  d_in[1];
    const int*   tsz    = (const int*)  d_in[2];
    const float* trans  = (const float*)d_in[3];
    float* out = (float*)d_out;

    float*          ws_c = (float*)d_ws;                                    // 16 KB
    unsigned short* ws_R = (unsigned short*)((char*)d_ws + 16384);          // 33.55 MB
    float*          ws_v = (float*)((char*)d_ws + 16384 + 33554432);        // 128 KB
    float*          ws_w = (float*)((char*)d_ws + 16384 + 33554432 + 131072);

    // 64 fac blocks (128 fwd + 128 bwd waves) + 1024 chunk blocks
    asg_k1<<<dim3(1088), dim3(256), 0, stream>>>(xin, target, tsz, trans,
                                                 ws_c, ws_R, ws_v, ws_w);
    asg_k2<<<dim3(B_), dim3(128), 0, stream>>>(xin, ws_c, ws_R, ws_v, ws_w, out);
}